// Round 7
// baseline (202.418 us; speedup 1.0000x reference)
//
#include <hip/hip_runtime.h>
#include <math.h>

#define HB 256   // hidden
#define UB 128   // attention units
#define BB 16    // batch
#define TD 128   // decoder steps
#define TE 1024  // encoder steps

#define CLAMP_W 7.0f
#define L2E2 2.8853900817779268f        // 2*log2(e)
#define ALPHA 1.52587890625e-05f        // 2^-16 (folded into Ea)
#define NEG2ALPHA (-3.0517578125e-05f)  // -2*ALPHA

// staged operand: exp2(2*log2e*clamp(w,+-7) + shift); tanh(a+e)=1-2/(EaEb+1).
// clamp +-7 never triggers on this data (|w| <~ 6); shift=-16 scales Ea so the
// 4-way merged denominator stays < 2^30-ish. Numerics identical to R4/R6 (passed).
__device__ __forceinline__ float stage_exp(float w, float shift) {
    float t = fminf(fmaxf(w, -CLAMP_W), CLAMP_W);
    return exp2f(fmaf(t, L2E2, shift));
}

// ---------------- projections (dec + enc, one grid) ----------------
// 1-wave blocks, lane = row in a 64-row slab (X loads coalesced dwordx4);
// block owns a u8 tile; W/bias wave-uniform -> scalar loads (SMEM pipe, no
// VMEM/LDS pressure). Outputs NATURAL row-major ([row][128u]) via a 2KB LDS
// transpose so stores are 8x32B segments per wave instead of 64x16B.
#define DEC_SLABS 32                     // 2048 rows / 64
#define ENC_SLABS 256                    // 16384 rows / 64
#define DEC_BLOCKS (16 * DEC_SLABS)      // 512
#define ENC_BLOCKS (16 * ENC_SLABS)      // 4096

__global__ __launch_bounds__(64) void proj_v7(
    const float* __restrict__ dec, const float* __restrict__ enc,
    const float* __restrict__ W1, const float* __restrict__ b1,
    const float* __restrict__ W2, const float* __restrict__ b2,
    float* __restrict__ Ea, float* __restrict__ Eb) {
    const int blk = blockIdx.x;
    const bool is_dec = blk < DEC_BLOCKS;
    const int rel   = is_dec ? blk : blk - DEC_BLOCKS;
    const int nslab = is_dec ? DEC_SLABS : ENC_SLABS;
    const int ut    = rel / nslab;           // 0..15 (ut-major for L2 reuse)
    const int slab  = rel - ut * nslab;
    const float* __restrict__ X    = is_dec ? dec : enc;
    const float* __restrict__ W    = is_dec ? W1 : W2;
    const float* __restrict__ bias = is_dec ? b1 : b2;
    float* __restrict__ dst        = is_dec ? Ea : Eb;

    const int l = threadIdx.x;               // 0..63 = row in slab
    const long row = (long)slab * 64 + l;
    const float* xr = X + row * HB;
    const int u0 = ut * 8;

    float acc[8];
    #pragma unroll
    for (int j = 0; j < 8; ++j) acc[j] = 0.f;

    for (int h = 0; h < HB; h += 8) {
        float4 x0 = *reinterpret_cast<const float4*>(xr + h);
        float4 x1 = *reinterpret_cast<const float4*>(xr + h + 4);
        float4 w[8][2];
        #pragma unroll
        for (int k = 0; k < 8; ++k) {        // uniform -> scalar loads
            w[k][0] = *reinterpret_cast<const float4*>(W + (h + k) * UB + u0);
            w[k][1] = *reinterpret_cast<const float4*>(W + (h + k) * UB + u0 + 4);
        }
        const float xk[8] = {x0.x, x0.y, x0.z, x0.w, x1.x, x1.y, x1.z, x1.w};
        #pragma unroll
        for (int k = 0; k < 8; ++k) {
            acc[0] = fmaf(xk[k], w[k][0].x, acc[0]);
            acc[1] = fmaf(xk[k], w[k][0].y, acc[1]);
            acc[2] = fmaf(xk[k], w[k][0].z, acc[2]);
            acc[3] = fmaf(xk[k], w[k][0].w, acc[3]);
            acc[4] = fmaf(xk[k], w[k][1].x, acc[4]);
            acc[5] = fmaf(xk[k], w[k][1].y, acc[5]);
            acc[6] = fmaf(xk[k], w[k][1].z, acc[6]);
            acc[7] = fmaf(xk[k], w[k][1].w, acc[7]);
        }
    }

    const float sh = is_dec ? -16.f : 0.f;
    __shared__ float tr[64][9];              // pad 9: conflict-free
    #pragma unroll
    for (int j = 0; j < 8; ++j)
        tr[l][j] = stage_exp(acc[j] + bias[u0 + j], sh);
    __syncthreads();

    const int uj = l & 7, rj = l >> 3;       // 8 u x 8 row-groups
    const long slabbase = (long)slab * 64;
    #pragma unroll
    for (int it = 0; it < 8; ++it) {
        const int r = it * 8 + rj;
        dst[(slabbase + r) * UB + u0 + uj] = tr[r][uj];
    }
}

// ---------------- raw scores (lane = t, e/V wave-uniform) ----------------
// Grid 512 (16 b x 32 s-chunks of 32), 512 thr = 8 waves = 4 wave-pairs.
// Wave-pair p owns 8 s; lane+wave-parity = t (128). Per u-half: thread's
// a-fragment (16 float4 = 64 VGPR) preloaded; inner loop operands all in
// registers/SGPRs -> pure VALU. Raw scores -> d_out via LDS transpose.
__global__ __launch_bounds__(512) void score_v7(
    const float* __restrict__ Ea,   // [B][TD][UB], 2^-16-scaled
    const float* __restrict__ Eb,   // [B][TE][UB]
    const float* __restrict__ V,    // [UB]
    float* __restrict__ outraw) {   // [B][TD][TE] raw scores
    const int tid = threadIdx.x;
    const int lane = tid & 63;
    const int wave = __builtin_amdgcn_readfirstlane(tid >> 6);  // 0..7
    const int pair = wave >> 1;                                  // 0..3
    const int t = (wave & 1) * 64 + lane;                        // 0..127
    const int i = blockIdx.x;
    const int b  = 2 * (i & 7) + ((i >> 3) >> 5);    // XCD-pinned batches
    const int sc0 = ((i >> 3) & 31) * 32;            // block s-base
    const int s0 = sc0 + pair * 8;                   // pair s-base

    const float* __restrict__ ap = Ea + ((long)b * TD + t) * UB;
    const float* __restrict__ ebase = Eb + ((long)b * TE + s0) * UB;
    const float alphav = ALPHA;

    float acc[8];
    #pragma unroll
    for (int ss = 0; ss < 8; ++ss) acc[ss] = 0.f;

    #pragma unroll
    for (int half = 0; half < 2; ++half) {
        float4 a[16];
        #pragma unroll
        for (int k = 0; k < 16; ++k)
            a[k] = *reinterpret_cast<const float4*>(ap + half * 64 + k * 4);
        const float* __restrict__ vp = V + half * 64;

        #pragma unroll
        for (int ss = 0; ss < 8; ++ss) {
            const float* __restrict__ ep = ebase + ss * UB + half * 64;
            float a8 = 0.f;
            #pragma unroll 4
            for (int u4 = 0; u4 < 16; ++u4) {
                float4 e = *reinterpret_cast<const float4*>(ep + u4 * 4);  // uniform
                float4 v = *reinterpret_cast<const float4*>(vp + u4 * 4);  // uniform
                float4 A = a[u4];
                float X0 = fmaf(A.x, e.x, alphav);
                float X1 = fmaf(A.y, e.y, alphav);
                float X2 = fmaf(A.z, e.z, alphav);
                float X3 = fmaf(A.w, e.w, alphav);
                float P01 = X0 * X1, P23 = X2 * X3;
                float N01 = fmaf(v.x, X1, v.y * X0);
                float N23 = fmaf(v.z, X3, v.w * X2);
                float N   = fmaf(N01, P23, N23 * P01);
                a8 = fmaf(N, __builtin_amdgcn_rcpf(P01 * P23), a8);
            }
            acc[ss] += a8;
        }
    }

    // transpose 128t x 32s through LDS, write coalesced 128B row segments
    __shared__ float tr[128][33];
    #pragma unroll
    for (int ss = 0; ss < 8; ++ss) tr[t][pair * 8 + ss] = NEG2ALPHA * acc[ss];
    __syncthreads();
    const int r  = tid >> 2;            // 0..127
    const int c0 = (tid & 3) * 8;       // 0/8/16/24
    float* orow = outraw + ((long)b * TD + r) * TE + sc0 + c0;
    #pragma unroll
    for (int k = 0; k < 8; ++k) orow[k] = tr[r][c0 + k];
}

// ---------------- in-place row softmax on d_out ----------------
__global__ __launch_bounds__(1024) void softmax_v7(float* __restrict__ out) {
    const long row = blockIdx.x;             // b*TD + t
    float* p = out + row * TE;
    const int tid = threadIdx.x;
    const int wv = tid >> 6, l = tid & 63;

    float x = p[tid];
    __shared__ float red[16];
    float m = x;
    #pragma unroll
    for (int off = 32; off > 0; off >>= 1) m = fmaxf(m, __shfl_xor(m, off, 64));
    if (l == 0) red[wv] = m;
    __syncthreads();
    #pragma unroll
    for (int k = 0; k < 16; ++k) m = fmaxf(m, red[k]);
    __syncthreads();
    float e = __expf(x - m);
    float s = e;
    #pragma unroll
    for (int off = 32; off > 0; off >>= 1) s += __shfl_xor(s, off, 64);
    if (l == 0) red[wv] = s;
    __syncthreads();
    s = 0.f;
    #pragma unroll
    for (int k = 0; k < 16; ++k) s += red[k];
    p[tid] = e * (1.f / s);
}

extern "C" void kernel_launch(void* const* d_in, const int* in_sizes, int n_in,
                              void* d_out, int out_size, void* d_ws, size_t ws_size,
                              hipStream_t stream) {
    const float* dec = (const float*)d_in[0];
    const float* enc = (const float*)d_in[1];
    const float* W1  = (const float*)d_in[2];
    const float* b1  = (const float*)d_in[3];
    const float* W2  = (const float*)d_in[4];
    const float* b2  = (const float*)d_in[5];
    const float* V   = (const float*)d_in[6];
    // d_in[7] = bv : softmax-invariant, unused
    float* out = (float*)d_out;

    float* Ea = (float*)d_ws;                  // [B][TD][UB]  1 MB (2^-16-scaled)
    float* Eb = Ea + (long)BB * TD * UB;       // [B][TE][UB]  8 MB

    proj_v7<<<DEC_BLOCKS + ENC_BLOCKS, 64, 0, stream>>>(dec, enc, W1, b1, W2, b2, Ea, Eb);
    score_v7<<<512, 512, 0, stream>>>(Ea, Eb, V, out);
    softmax_v7<<<BB * TD, 1024, 0, stream>>>(out);
}

// Round 8
// 76.398 us; speedup vs baseline: 2.6495x; 2.6495x over previous
//
#include <hip/hip_runtime.h>
#include <math.h>

#define HB 256   // hidden
#define UB 128   // attention units
#define BB 16    // batch
#define TD 128   // decoder steps
#define TE 1024  // encoder steps

#define CLAMP_W 7.0f
#define L2E2 2.8853900817779268f        // 2*log2(e)
#define ALPHA 1.52587890625e-05f        // 2^-16 (folded into Ea)
#define NEG2ALPHA (-3.0517578125e-05f)  // -2*ALPHA

// zero-instruction scheduling pins: force value materialized (and load
// completed) at this program point; cannot be sunk past it. No runtime cost.
#define PINV(x) asm volatile("" : "+v"(x))
#define PINS(x) asm volatile("" : "+s"(x))
#define PINV4(q) do { PINV((q).x); PINV((q).y); PINV((q).z); PINV((q).w); } while (0)
#define PINS4(q) do { PINS((q).x); PINS((q).y); PINS((q).z); PINS((q).w); } while (0)

// staged operand: exp2(2*log2e*clamp(w,+-7) + shift); tanh(a+e)=1-2/(EaEb+1).
// clamp +-7 never triggers on this data (|w| <~ 6); shift=-16 scales Ea so the
// 4-way merged denominator stays bounded. Numerics identical to R4/R6 (passed).
__device__ __forceinline__ float stage_exp(float w, float shift) {
    float t = fminf(fmaxf(w, -CLAMP_W), CLAMP_W);
    return exp2f(fmaf(t, L2E2, shift));
}

// ---------------- projections (dec + enc, one grid) ----------------
// 1-wave blocks, lane = row in a 64-row slab (X per-lane coalesced dwordx4);
// block owns u8 tile; W/bias wave-uniform -> scalar loads. Depth-1 software
// pipeline on both X and W, enforced with pins. Output layout [b][u4][pos][4].
#define DEC_SLABS 32                     // 2048 rows / 64
#define ENC_SLABS 256                    // 16384 rows / 64
#define DEC_BLOCKS (16 * DEC_SLABS)      // 512
#define ENC_BLOCKS (16 * ENC_SLABS)      // 4096

__global__ __launch_bounds__(64) void proj_v8(
    const float* __restrict__ dec, const float* __restrict__ enc,
    const float* __restrict__ W1, const float* __restrict__ b1,
    const float* __restrict__ W2, const float* __restrict__ b2,
    float* __restrict__ Ea, float* __restrict__ Eb) {
    const int blk = blockIdx.x;
    const bool is_dec = blk < DEC_BLOCKS;
    const int rel   = is_dec ? blk : blk - DEC_BLOCKS;
    const int nslab = is_dec ? DEC_SLABS : ENC_SLABS;
    const int ut    = rel / nslab;           // 0..15 (ut-major for W/L2 reuse)
    const int slab  = rel - ut * nslab;
    const float* __restrict__ X    = is_dec ? dec : enc;
    const float* __restrict__ W    = is_dec ? W1 : W2;
    const float* __restrict__ bias = is_dec ? b1 : b2;

    const int l = threadIdx.x;               // 0..63 = row in slab
    const long row = (long)slab * 64 + l;
    const float* xr = X + row * HB;
    const int u0 = ut * 8;

    float acc[8];
    #pragma unroll
    for (int j = 0; j < 8; ++j) acc[j] = 0.f;

    float4 xC, xN, wC[4][2], wN[4][2];
    xC = *reinterpret_cast<const float4*>(xr);
    #pragma unroll
    for (int k = 0; k < 4; ++k) {
        wC[k][0] = *reinterpret_cast<const float4*>(W + k * UB + u0);
        wC[k][1] = *reinterpret_cast<const float4*>(W + k * UB + u0 + 4);
    }

    #pragma unroll 2
    for (int h = 0; h < HB; h += 4) {
        const int hn = (h + 4 < HB) ? h + 4 : 0;   // wrap: harmless reload
        xN = *reinterpret_cast<const float4*>(xr + hn);
        #pragma unroll
        for (int k = 0; k < 4; ++k) {
            wN[k][0] = *reinterpret_cast<const float4*>(W + (hn + k) * UB + u0);
            wN[k][1] = *reinterpret_cast<const float4*>(W + (hn + k) * UB + u0 + 4);
        }
        const float xk[4] = {xC.x, xC.y, xC.z, xC.w};
        #pragma unroll
        for (int k = 0; k < 4; ++k) {
            acc[0] = fmaf(xk[k], wC[k][0].x, acc[0]);
            acc[1] = fmaf(xk[k], wC[k][0].y, acc[1]);
            acc[2] = fmaf(xk[k], wC[k][0].z, acc[2]);
            acc[3] = fmaf(xk[k], wC[k][0].w, acc[3]);
            acc[4] = fmaf(xk[k], wC[k][1].x, acc[4]);
            acc[5] = fmaf(xk[k], wC[k][1].y, acc[5]);
            acc[6] = fmaf(xk[k], wC[k][1].z, acc[6]);
            acc[7] = fmaf(xk[k], wC[k][1].w, acc[7]);
        }
        PINV4(xN);
        #pragma unroll
        for (int k = 0; k < 4; ++k) { PINS4(wN[k][0]); PINS4(wN[k][1]); }
        xC = xN;
        #pragma unroll
        for (int k = 0; k < 4; ++k) { wC[k][0] = wN[k][0]; wC[k][1] = wN[k][1]; }
    }

    float4 bv0 = *reinterpret_cast<const float4*>(bias + u0);
    float4 bv1 = *reinterpret_cast<const float4*>(bias + u0 + 4);
    const float sh = is_dec ? -16.f : 0.f;
    float4 q0 = make_float4(stage_exp(acc[0] + bv0.x, sh), stage_exp(acc[1] + bv0.y, sh),
                            stage_exp(acc[2] + bv0.z, sh), stage_exp(acc[3] + bv0.w, sh));
    float4 q1 = make_float4(stage_exp(acc[4] + bv1.x, sh), stage_exp(acc[5] + bv1.y, sh),
                            stage_exp(acc[6] + bv1.z, sh), stage_exp(acc[7] + bv1.w, sh));

    if (is_dec) {                            // Ea [b][u4][t][4]
        const long bq = row >> 7;
        const int  t  = (int)(row & (TD - 1));
        float4* dst = reinterpret_cast<float4*>(Ea);
        dst[(bq * 32 + ut * 2 + 0) * TD + t] = q0;
        dst[(bq * 32 + ut * 2 + 1) * TD + t] = q1;
    } else {                                 // Eb [b][u4][s][4]
        const long bq = row >> 10;
        const int  s  = (int)(row & (TE - 1));
        float4* dst = reinterpret_cast<float4*>(Eb);
        dst[(bq * 32 + ut * 2 + 0) * TE + s] = q0;
        dst[(bq * 32 + ut * 2 + 1) * TE + s] = q1;
    }
}

// ---------------- scores + fused softmax ----------------
// Grid 256 (1 block/CU, XCD-pinned b), 1024 thr = 16 waves. Thread: s = tid,
// 8 t-rows. Depth-1 software pipeline: next u4's a-tile (2x s_load_dwordx16)
// + V (s_loadx4) + e (per-lane coalesced dwordx4) loaded each iter, pinned
// after current compute. Inner math: 4-way exact division merge,
// 13 VALU + 1 rcp per 4 u per row. VALU floor ~12 us.
__global__ __launch_bounds__(1024) void score_v8(
    const float* __restrict__ Ea4,   // [B][32][TD][4], 2^-16-scaled
    const float4* __restrict__ Eb4,  // [B][32][TE]
    const float* __restrict__ V,     // [UB]
    float* __restrict__ out) {       // [B, TD, TE]
    const int tid = threadIdx.x;
    const int wv = tid >> 6, l = tid & 63;
    const int i = blockIdx.x;
    const int b  = 2 * (i & 7) + ((i >> 3) >> 4);
    const int t0 = ((i >> 3) & 15) * 8;

    const float*  ab = Ea4 + ((long)b * 32 * TD) * 4;   // + (u4*TD + t0)*4
    const float4* ep = Eb4 + (long)b * 32 * TE + tid;   // + u4*TE
    const float alphav = ALPHA;

    float acc[8];
    #pragma unroll
    for (int t = 0; t < 8; ++t) acc[t] = 0.f;

    float4 aC[8], aN[8], vC, vN, eC, eN;
#define SLOAD(AB, VB, EB, U4) do {                                        \
        const float* _a = ab + ((long)(U4) * TD + t0) * 4;                \
        _Pragma("unroll")                                                 \
        for (int t = 0; t < 8; ++t)                                       \
            AB[t] = *reinterpret_cast<const float4*>(_a + t * 4);         \
        VB = *reinterpret_cast<const float4*>(V + (U4) * 4);              \
        EB = ep[(long)(U4) * TE];                                         \
    } while (0)

#define SCOMP(AB, VB, EB) do {                                            \
        _Pragma("unroll")                                                 \
        for (int t = 0; t < 8; ++t) {                                     \
            float4 A = AB[t];                                             \
            float X0 = fmaf(A.x, (EB).x, alphav);                         \
            float X1 = fmaf(A.y, (EB).y, alphav);                         \
            float X2 = fmaf(A.z, (EB).z, alphav);                         \
            float X3 = fmaf(A.w, (EB).w, alphav);                         \
            float P01 = X0 * X1, P23 = X2 * X3;                           \
            float N01 = fmaf((VB).x, X1, (VB).y * X0);                    \
            float N23 = fmaf((VB).z, X3, (VB).w * X2);                    \
            float N   = fmaf(N01, P23, N23 * P01);                        \
            acc[t] = fmaf(N, __builtin_amdgcn_rcpf(P01 * P23), acc[t]);   \
        }                                                                 \
    } while (0)

    SLOAD(aC, vC, eC, 0);
    #pragma unroll 2
    for (int u4 = 0; u4 < 32; ++u4) {
        const int p = (u4 + 1 < 32) ? u4 + 1 : 0;   // wrap: harmless reload
        SLOAD(aN, vN, eN, p);
        SCOMP(aC, vC, eC);
        #pragma unroll
        for (int t = 0; t < 8; ++t) PINS4(aN[t]);
        PINS4(vN);
        PINV4(eN);
        #pragma unroll
        for (int t = 0; t < 8; ++t) aC[t] = aN[t];
        vC = vN; eC = eN;
    }
#undef SLOAD
#undef SCOMP

    float sc[8];
    #pragma unroll
    for (int t = 0; t < 8; ++t) sc[t] = NEG2ALPHA * acc[t];

    __shared__ float red[8][16];
    #pragma unroll
    for (int t = 0; t < 8; ++t) {
        float x = sc[t];
        #pragma unroll
        for (int off = 32; off > 0; off >>= 1) x = fmaxf(x, __shfl_xor(x, off, 64));
        if (l == 0) red[t][wv] = x;
    }
    __syncthreads();
    float m[8];
    #pragma unroll
    for (int t = 0; t < 8; ++t) {
        float x = red[t][0];
        #pragma unroll
        for (int k = 1; k < 16; ++k) x = fmaxf(x, red[t][k]);
        m[t] = x;
    }
    __syncthreads();
    #pragma unroll
    for (int t = 0; t < 8; ++t) {
        sc[t] = __expf(sc[t] - m[t]);
        float x = sc[t];
        #pragma unroll
        for (int off = 32; off > 0; off >>= 1) x += __shfl_xor(x, off, 64);
        if (l == 0) red[t][wv] = x;
    }
    __syncthreads();
    #pragma unroll
    for (int t = 0; t < 8; ++t) {
        float x = red[t][0];
        #pragma unroll
        for (int k = 1; k < 16; ++k) x += red[t][k];
        out[((long)b * TD + t0 + t) * TE + tid] = sc[t] * (1.f / x);
    }
}

extern "C" void kernel_launch(void* const* d_in, const int* in_sizes, int n_in,
                              void* d_out, int out_size, void* d_ws, size_t ws_size,
                              hipStream_t stream) {
    const float* dec = (const float*)d_in[0];
    const float* enc = (const float*)d_in[1];
    const float* W1  = (const float*)d_in[2];
    const float* b1  = (const float*)d_in[3];
    const float* W2  = (const float*)d_in[4];
    const float* b2  = (const float*)d_in[5];
    const float* V   = (const float*)d_in[6];
    // d_in[7] = bv : softmax-invariant, unused
    float* out = (float*)d_out;

    float* Ea = (float*)d_ws;                  // [B][32][TD][4]  1 MB (2^-16-scaled)
    float* Eb = Ea + (long)BB * 32 * TD * 4;   // [B][32][TE][4]  8 MB

    proj_v8<<<DEC_BLOCKS + ENC_BLOCKS, 64, 0, stream>>>(dec, enc, W1, b1, W2, b2, Ea, Eb);
    score_v8<<<256, 1024, 0, stream>>>(Ea, (const float4*)Eb, V, out);
}